// Round 15
// baseline (1191.485 us; speedup 1.0000x reference)
//
#include <hip/hip_runtime.h>
#include <hip/hip_fp16.h>
#include <hip/hip_cooperative_groups.h>

namespace cg = cooperative_groups;

// NNConv GNN: 5 conv layers, fixed graph (N=40000, E=400000).
// R-ladder: 317 -> 228 (scan fix) -> 205 (wave-per-node) -> 190 (agg+pre
// fusion) -> 184 (fp16-packed Y) -> 148.6 (bucketed edata, 7 dispatches,
// launch_bounds).
// R14 analysis: ~40-50us of kernel work vs 148.6 wall -> ~100us is
// inter-dispatch drain (7 dependent graph nodes).
// R15: ONE cooperative kernel, grid.sync() between layers; grid=1024x256
// (exactly 4 blocks/CU co-resident); counts zeroed via hipMemsetAsync;
// fallback to multi-dispatch if cooperative launch errors.

#define NEG_SLOPE 0.01f
#define CAP 48
#define GRID 1024
#define BLK 256

struct Params {
    const int* src; const int* dst; const float* ea;
    const float* x;
    const float* nn1w; const float* nn1b; const float* root1; const float* bias1;
    const float* nn2w; const float* nn2b; const float* root2; const float* bias2;
    const float* nn3w; const float* nn3b; const float* root3; const float* bias3;
    int* counts; uint2* edata; uint2* Ya; uint2* Yb; float* Y6f; uint2* Y6pk;
    float* out; int N; int E;
};

__device__ __forceinline__ unsigned pk2(float a, float b) {
    __half2 h = __floats2half2_rn(a, b);
    return *reinterpret_cast<unsigned*>(&h);
}
__device__ __forceinline__ float2 upk2(unsigned u) {
    __half2 h = *reinterpret_cast<__half2*>(&u);
    return __half22float2(h);
}

__device__ __forceinline__ float edge_term(uint2 ed, const uint2* __restrict__ Yin, int o) {
    int s = (int)ed.x;
    float2 eaf = upk2(ed.y);
    uint2 ys = Yin[(size_t)s * 16 + o];
    float2 y01 = upk2(ys.x);
    float2 y23 = upk2(ys.y);
    return fmaf(eaf.x, y01.x, fmaf(eaf.y, y01.y, y23.x));
}

__device__ __forceinline__ void fill_one(const Params& P, int e) {
    int d = P.dst[e];
    int slot = atomicAdd(&P.counts[d], 1);
    if (slot < CAP)
        P.edata[(size_t)d * CAP + slot] =
            make_uint2((unsigned)P.src[e], pk2(P.ea[2 * e], P.ea[2 * e + 1]));
}

__device__ __forceinline__ void pre1_one(const Params& P, int t) {
    int n = t >> 4, o = t & 15;
    float x0 = P.x[n * 2], x1 = P.x[n * 2 + 1];
    int k0 = o, k1 = 16 + o;
    float a0 = x0 * P.nn1w[2 * k0] + x1 * P.nn1w[2 * k1];
    float a1 = x0 * P.nn1w[2 * k0 + 1] + x1 * P.nn1w[2 * k1 + 1];
    float ab = x0 * P.nn1b[k0] + x1 * P.nn1b[k1];
    float ar = x0 * P.root1[k0] + x1 * P.root1[k1];
    P.Ya[(size_t)n * 16 + o] = make_uint2(pk2(a0, a1), pk2(ab, ar));
}

// agg of one fout=16 layer for node w -> r (lrelu'd, channel lane&15 in all
// lanes); returns r.
__device__ __forceinline__ float agg16_core(const Params& P, const uint2* __restrict__ Yin,
                                            const float* __restrict__ bias, int w, int lane) {
    int o = lane & 15, g = lane >> 4;
    int deg = P.counts[w]; deg = deg < CAP ? deg : CAP;
    const uint2* row = P.edata + (size_t)w * CAP;
    float acc = 0.f;
    int k = g;
    for (; k + 4 < deg; k += 8) {
        uint2 e0 = row[k], e1 = row[k + 4];
        acc += edge_term(e0, Yin, o);
        acc += edge_term(e1, Yin, o);
    }
    if (k < deg) acc += edge_term(row[k], Yin, o);
    acc += __shfl_xor(acc, 16, 64);
    acc += __shfl_xor(acc, 32, 64);
    float invdeg = 1.0f / (float)(deg > 1 ? deg : 1);
    float rootown = upk2(Yin[(size_t)w * 16 + o].y).y;
    float r = acc * invdeg + rootown + bias[o];
    return r > 0.f ? r : NEG_SLOPE * r;
}

__device__ __forceinline__ void aggpre_one(const Params& P, const uint2* __restrict__ Yin,
                                           const float* __restrict__ bias,
                                           uint2* __restrict__ Yout, int m3base, bool first,
                                           int w, int lane) {
    int o = lane & 15, g = lane >> 4;
    float r = agg16_core(P, Yin, bias, w, lane);
    // next-layer projections: blk=g (0:A0 1:A1 2:B 3:root), out col = o
    {
        const float* Mp = g == 0 ? P.nn2w : g == 1 ? P.nn2w + 1 : g == 2 ? P.nn2b : P.root2;
        int st = g < 2 ? 2 : 1;
        float y = 0.f;
#pragma unroll
        for (int i = 0; i < 16; ++i) {
            float xi = __shfl(r, i, 64);
            y = fmaf(xi, Mp[(i * 16 + o) * st], y);
        }
        float p16 = __shfl_xor(y, 16, 64);
        float p32 = __shfl_xor(y, 32, 64);
        float p48 = __shfl_xor(y, 48, 64);
        if (g == 0) Yout[(size_t)w * 16 + o] = make_uint2(pk2(y, p16), pk2(p32, p48));
    }
    // final-layer f32 partial: j=lane&7 (blk=j>>1, oo=j&1), g8 owns c=2g8,2g8+1
    {
        int j = lane & 7, g8 = lane >> 3;
        int blk = j >> 1, oo = j & 1;
        const float* Mp = blk == 0 ? P.nn3w : blk == 1 ? P.nn3w + 1 : blk == 2 ? P.nn3b : P.root3;
        int st = blk < 2 ? 2 : 1;
        float p = 0.f;
#pragma unroll
        for (int cc = 0; cc < 2; ++cc) {
            int c = g8 * 2 + cc;
            float xi = __shfl(r, c, 64);
            p = fmaf(xi, Mp[((m3base + c) * 2 + oo) * st], p);
        }
        p += __shfl_xor(p, 8, 64);
        p += __shfl_xor(p, 16, 64);
        p += __shfl_xor(p, 32, 64);
        if (lane < 8) {
            float* y6 = P.Y6f + (size_t)w * 8 + oo * 4 + blk;
            *y6 = first ? p : (*y6 + p);
        }
    }
}

__device__ __forceinline__ void agg4_one(const Params& P, const uint2* __restrict__ Yin,
                                         const float* __restrict__ bias, int m3base,
                                         int w, int lane) {
    float r = agg16_core(P, Yin, bias, w, lane);
    int j = lane & 7, g8 = lane >> 3;
    int blk = j >> 1, oo = j & 1;
    const float* Mp = blk == 0 ? P.nn3w : blk == 1 ? P.nn3w + 1 : blk == 2 ? P.nn3b : P.root3;
    int st = blk < 2 ? 2 : 1;
    float p = 0.f;
#pragma unroll
    for (int cc = 0; cc < 2; ++cc) {
        int c = g8 * 2 + cc;
        float xi = __shfl(r, c, 64);
        p = fmaf(xi, Mp[((m3base + c) * 2 + oo) * st], p);
    }
    p += __shfl_xor(p, 8, 64);
    p += __shfl_xor(p, 16, 64);
    p += __shfl_xor(p, 32, 64);
    float tot = P.Y6f[(size_t)w * 8 + oo * 4 + blk] + p;
    float t1 = __shfl_xor(tot, 2, 64);
    float t2 = __shfl_xor(tot, 4, 64);
    float t3 = __shfl_xor(tot, 6, 64);
    if (lane < 2)
        P.Y6pk[(size_t)w * 2 + lane] = make_uint2(pk2(tot, t1), pk2(t2, t3));
}

__device__ __forceinline__ void agg2_one(const Params& P, int w, int lane) {
    int o = lane & 1, g = lane >> 1;
    int deg = P.counts[w]; deg = deg < CAP ? deg : CAP;
    const uint2* row = P.edata + (size_t)w * CAP;
    float acc = 0.f;
    for (int k = g; k < deg; k += 32) {
        uint2 ed = row[k];
        int s = (int)ed.x;
        float2 eaf = upk2(ed.y);
        uint2 q = P.Y6pk[(size_t)s * 2 + o];
        float2 q01 = upk2(q.x);
        float2 q23 = upk2(q.y);
        acc += fmaf(eaf.x, q01.x, fmaf(eaf.y, q01.y, q23.x));
    }
#pragma unroll
    for (int m = 2; m <= 32; m <<= 1) acc += __shfl_xor(acc, m, 64);
    if (lane < 2) {
        float invdeg = 1.0f / (float)(deg > 1 ? deg : 1);
        float rootown = upk2(P.Y6pk[(size_t)w * 2 + o].y).y;
        P.out[(size_t)w * 2 + o] = acc * invdeg + rootown + P.bias3[o];
    }
}

// ---------- single cooperative kernel ----------
__global__ void __launch_bounds__(BLK, 4) fused_kernel(Params P) {
    cg::grid_group grid = cg::this_grid();
    const int tid = blockIdx.x * BLK + threadIdx.x;
    const int nth = GRID * BLK;
    const int lane = threadIdx.x & 63;
    const int wid = tid >> 6;
    const int nw = nth >> 6;

    // phase 1: fill buckets (counts pre-zeroed by memset) + layer-1 pre
    for (int e = tid; e < P.E; e += nth) fill_one(P, e);
    for (int t = tid; t < P.N * 16; t += nth) pre1_one(P, t);
    __threadfence(); grid.sync();

    // layers 1-3: agg + next-layer pre + final-layer partial (ping-pong)
    for (int w = wid; w < P.N; w += nw) aggpre_one(P, P.Ya, P.bias1, P.Yb, 0, true, w, lane);
    __threadfence(); grid.sync();
    for (int w = wid; w < P.N; w += nw) aggpre_one(P, P.Yb, P.bias2, P.Ya, 16, false, w, lane);
    __threadfence(); grid.sync();
    for (int w = wid; w < P.N; w += nw) aggpre_one(P, P.Ya, P.bias2, P.Yb, 32, false, w, lane);
    __threadfence(); grid.sync();
    // layer 4: agg + pack final Y6
    for (int w = wid; w < P.N; w += nw) agg4_one(P, P.Yb, P.bias2, 48, w, lane);
    __threadfence(); grid.sync();
    // final aggregation (fout=2, no lrelu)
    for (int w = wid; w < P.N; w += nw) agg2_one(P, w, lane);
}

// ---------- fallback multi-dispatch wrappers ----------
__global__ void __launch_bounds__(BLK, 4) k_fillpre(Params P, int nFill) {
    if ((int)blockIdx.x < nFill) {
        int e = blockIdx.x * BLK + threadIdx.x;
        if (e < P.E) fill_one(P, e);
    } else {
        int t = (blockIdx.x - nFill) * BLK + threadIdx.x;
        if (t < P.N * 16) pre1_one(P, t);
    }
}
__global__ void __launch_bounds__(BLK, 4) k_aggpre(Params P, const uint2* Yin, const float* bias,
                                                   uint2* Yout, int m3base, int first) {
    int w = (int)((blockIdx.x * blockDim.x + threadIdx.x) >> 6);
    if (w < P.N) aggpre_one(P, Yin, bias, Yout, m3base, first != 0, w, threadIdx.x & 63);
}
__global__ void __launch_bounds__(BLK, 4) k_agg4(Params P, const uint2* Yin, const float* bias,
                                                 int m3base) {
    int w = (int)((blockIdx.x * blockDim.x + threadIdx.x) >> 6);
    if (w < P.N) agg4_one(P, Yin, bias, m3base, w, threadIdx.x & 63);
}
__global__ void __launch_bounds__(BLK, 4) k_agg2(Params P) {
    int w = (int)((blockIdx.x * blockDim.x + threadIdx.x) >> 6);
    if (w < P.N) agg2_one(P, w, threadIdx.x & 63);
}

extern "C" void kernel_launch(void* const* d_in, const int* in_sizes, int n_in,
                              void* d_out, int out_size, void* d_ws, size_t ws_size,
                              hipStream_t stream) {
    const float* x     = (const float*)d_in[0];
    const int*   eidx  = (const int*)d_in[1];
    const float* eattr = (const float*)d_in[2];

    const int N = in_sizes[0] / 2;
    const int E = in_sizes[2] / 2;

    char* ws = (char*)d_ws;
    size_t off = 0;
    auto alloc = [&](size_t bytes, size_t align) -> char* {
        off = (off + align - 1) / align * align;
        char* p = ws + off;
        off += bytes;
        return p;
    };
    int*   counts = (int*)alloc((size_t)N * 4, 16);
    uint2* edata  = (uint2*)alloc((size_t)N * CAP * 8, 16);
    uint2* Ya     = (uint2*)alloc((size_t)N * 16 * 8, 16);
    uint2* Yb     = (uint2*)alloc((size_t)N * 16 * 8, 16);
    float* Y6f    = (float*)alloc((size_t)N * 8 * 4, 16);
    uint2* Y6pk   = (uint2*)alloc((size_t)N * 2 * 8, 16);
    (void)ws_size; (void)n_in; (void)out_size;

    Params P;
    P.src = eidx; P.dst = eidx + E; P.ea = eattr; P.x = x;
    P.nn1w = (const float*)d_in[3];  P.nn1b = (const float*)d_in[4];
    P.root1 = (const float*)d_in[5]; P.bias1 = (const float*)d_in[6];
    P.nn2w = (const float*)d_in[7];  P.nn2b = (const float*)d_in[8];
    P.root2 = (const float*)d_in[9]; P.bias2 = (const float*)d_in[10];
    P.nn3w = (const float*)d_in[11]; P.nn3b = (const float*)d_in[12];
    P.root3 = (const float*)d_in[13]; P.bias3 = (const float*)d_in[14];
    P.counts = counts; P.edata = edata; P.Ya = Ya; P.Yb = Yb;
    P.Y6f = Y6f; P.Y6pk = Y6pk;
    P.out = (float*)d_out; P.N = N; P.E = E;

    hipMemsetAsync(counts, 0, (size_t)N * 4, stream);

    void* args[] = { &P };
    hipError_t err = hipLaunchCooperativeKernel((const void*)fused_kernel,
                                                dim3(GRID), dim3(BLK), args, 0, stream);
    if (err != hipSuccess) {
        // fallback: proven R14 multi-dispatch path (same device bodies)
        const int waveblocks = (N * 64 + BLK - 1) / BLK;
        const int nFill = (E + BLK - 1) / BLK;
        const int nPre1 = (N * 16 + BLK - 1) / BLK;
        k_fillpre<<<nFill + nPre1, BLK, 0, stream>>>(P, nFill);
        k_aggpre<<<waveblocks, BLK, 0, stream>>>(P, Ya, P.bias1, Yb, 0, 1);
        k_aggpre<<<waveblocks, BLK, 0, stream>>>(P, Yb, P.bias2, Ya, 16, 0);
        k_aggpre<<<waveblocks, BLK, 0, stream>>>(P, Ya, P.bias2, Yb, 32, 0);
        k_agg4<<<waveblocks, BLK, 0, stream>>>(P, Yb, P.bias2, 48);
        k_agg2<<<waveblocks, BLK, 0, stream>>>(P);
    }
}

// Round 16
// 148.139 us; speedup vs baseline: 8.0430x; 8.0430x over previous
//
#include <hip/hip_runtime.h>
#include <hip/hip_fp16.h>

// NNConv GNN: 5 conv layers, fixed graph (N=40000, E=400000).
// R-ladder: 317 -> 228 (scan fix) -> 205 (wave-per-node) -> 190 (agg+pre
// fusion) -> 184 (fp16-packed Y) -> 148.6 (bucketed edata, launch_bounds).
// R15: cooperative single-kernel REGRESSED 8x (1191us): grid.sync() across
//      1024 blocks costs ~240us each on MI355X. Dispatch boundaries win.
//      Useful datum: full fused body = 52 VGPR.
// R16: back to R14 multi-dispatch; zero kernel -> hipMemsetAsync (6 kernel
//      dispatches); __launch_bounds__(256,8) (52 VGPR fits 64) doubles
//      resident blocks 1024->2048, halving latency-bound gather rounds.

#define NEG_SLOPE 0.01f
#define CAP 48
#define BLK 256

__device__ __forceinline__ unsigned pk2(float a, float b) {
    __half2 h = __floats2half2_rn(a, b);
    return *reinterpret_cast<unsigned*>(&h);
}
__device__ __forceinline__ float2 upk2(unsigned u) {
    __half2 h = *reinterpret_cast<__half2*>(&u);
    return __half22float2(h);
}

// blocks [0,nFill): count+scatter in one pass (bucket slot = atomic return);
// blocks [nFill,..): layer-1 projections (fin=2) packed fp16 into Ypk.
__global__ void __launch_bounds__(BLK, 8)
fillpre_kernel(const int* __restrict__ src, const int* __restrict__ dst,
               const float* __restrict__ ea, int* __restrict__ counts,
               uint2* __restrict__ edata, int E, int nFill,
               const float* __restrict__ x,
               const float* __restrict__ nnw, const float* __restrict__ nnb,
               const float* __restrict__ root,
               uint2* __restrict__ Ypk, int N) {
    if ((int)blockIdx.x < nFill) {
        int e = blockIdx.x * BLK + threadIdx.x;
        if (e >= E) return;
        int d = dst[e];
        int slot = atomicAdd(&counts[d], 1);
        if (slot < CAP)
            edata[(size_t)d * CAP + slot] =
                make_uint2((unsigned)src[e], pk2(ea[2 * e], ea[2 * e + 1]));
    } else {
        int t = (blockIdx.x - nFill) * BLK + threadIdx.x;
        int n = t >> 4, o = t & 15;
        if (n >= N) return;
        float x0 = x[n * 2], x1 = x[n * 2 + 1];
        int k0 = o, k1 = 16 + o;
        float a0 = x0 * nnw[2 * k0] + x1 * nnw[2 * k1];
        float a1 = x0 * nnw[2 * k0 + 1] + x1 * nnw[2 * k1 + 1];
        float ab = x0 * nnb[k0] + x1 * nnb[k1];
        float ar = x0 * root[k0] + x1 * root[k1];
        Ypk[(size_t)n * 16 + o] = make_uint2(pk2(a0, a1), pk2(ab, ar));
    }
}

__device__ __forceinline__ float edge_term(uint2 ed, const uint2* __restrict__ Yin, int o) {
    int s = (int)ed.x;
    float2 eaf = upk2(ed.y);
    uint2 ys = Yin[(size_t)s * 16 + o];
    float2 y01 = upk2(ys.x);
    float2 y23 = upk2(ys.y);
    return fmaf(eaf.x, y01.x, fmaf(eaf.y, y01.y, y23.x));
}

// Fused: wave-per-node agg of layer l (fout=16, lrelu) -> r; next-layer
// projections -> Yout (packed fp16); final-layer f32 partial into Y6f.
__global__ void __launch_bounds__(BLK, 8)
aggpre16L_kernel(const int* __restrict__ counts, const uint2* __restrict__ edata,
                 const uint2* __restrict__ Yin, const float* __restrict__ bias,
                 const float* __restrict__ nnw2, const float* __restrict__ nnb2,
                 const float* __restrict__ root2,
                 const float* __restrict__ nnw3, const float* __restrict__ nnb3,
                 const float* __restrict__ root3,
                 uint2* __restrict__ Yout, float* __restrict__ Y6f,
                 int m3base, int first, int N) {
    int w = (int)((blockIdx.x * blockDim.x + threadIdx.x) >> 6);
    if (w >= N) return;
    int lane = threadIdx.x & 63;
    int o = lane & 15, g = lane >> 4;
    int deg = counts[w]; deg = deg < CAP ? deg : CAP;
    const uint2* row = edata + (size_t)w * CAP;
    float acc = 0.f;
    int k = g;
    for (; k + 4 < deg; k += 8) {  // 2 independent gather chains
        uint2 e0 = row[k], e1 = row[k + 4];
        acc += edge_term(e0, Yin, o);
        acc += edge_term(e1, Yin, o);
    }
    if (k < deg) acc += edge_term(row[k], Yin, o);
    acc += __shfl_xor(acc, 16, 64);
    acc += __shfl_xor(acc, 32, 64);
    float invdeg = 1.0f / (float)(deg > 1 ? deg : 1);
    float rootown = upk2(Yin[(size_t)w * 16 + o].y).y;
    float r = acc * invdeg + rootown + bias[o];
    r = r > 0.f ? r : NEG_SLOPE * r;  // layer output, channel o in all lanes
    // next-layer projections: blk=g (0:A0 1:A1 2:B 3:root), out col = o
    {
        const float* Mp = g == 0 ? nnw2 : g == 1 ? nnw2 + 1 : g == 2 ? nnb2 : root2;
        int st = g < 2 ? 2 : 1;
        float y = 0.f;
#pragma unroll
        for (int i = 0; i < 16; ++i) {
            float xi = __shfl(r, i, 64);
            y = fmaf(xi, Mp[(i * 16 + o) * st], y);
        }
        float p16 = __shfl_xor(y, 16, 64);
        float p32 = __shfl_xor(y, 32, 64);
        float p48 = __shfl_xor(y, 48, 64);
        if (g == 0) Yout[(size_t)w * 16 + o] = make_uint2(pk2(y, p16), pk2(p32, p48));
    }
    // final-layer f32 partial: j=lane&7 (blk=j>>1, oo=j&1), g8 owns c=2g8,2g8+1
    {
        int j = lane & 7, g8 = lane >> 3;
        int blk = j >> 1, oo = j & 1;
        const float* Mp = blk == 0 ? nnw3 : blk == 1 ? nnw3 + 1 : blk == 2 ? nnb3 : root3;
        int st = blk < 2 ? 2 : 1;
        float p = 0.f;
#pragma unroll
        for (int cc = 0; cc < 2; ++cc) {
            int c = g8 * 2 + cc;
            float xi = __shfl(r, c, 64);
            p = fmaf(xi, Mp[((m3base + c) * 2 + oo) * st], p);
        }
        p += __shfl_xor(p, 8, 64);
        p += __shfl_xor(p, 16, 64);
        p += __shfl_xor(p, 32, 64);
        if (lane < 8) {
            float* y6 = Y6f + (size_t)w * 8 + oo * 4 + blk;
            *y6 = first ? p : (*y6 + p);
        }
    }
}

// Layer-4: agg (lrelu) + final Y6 sum, packed fp16 to Y6pk.
__global__ void __launch_bounds__(BLK, 8)
agg4_kernel(const int* __restrict__ counts, const uint2* __restrict__ edata,
            const uint2* __restrict__ Yin, const float* __restrict__ bias,
            const float* __restrict__ nnw3, const float* __restrict__ nnb3,
            const float* __restrict__ root3,
            const float* __restrict__ Y6f, uint2* __restrict__ Y6pk,
            int m3base, int N) {
    int w = (int)((blockIdx.x * blockDim.x + threadIdx.x) >> 6);
    if (w >= N) return;
    int lane = threadIdx.x & 63;
    int o = lane & 15, g = lane >> 4;
    int deg = counts[w]; deg = deg < CAP ? deg : CAP;
    const uint2* row = edata + (size_t)w * CAP;
    float acc = 0.f;
    int k = g;
    for (; k + 4 < deg; k += 8) {
        uint2 e0 = row[k], e1 = row[k + 4];
        acc += edge_term(e0, Yin, o);
        acc += edge_term(e1, Yin, o);
    }
    if (k < deg) acc += edge_term(row[k], Yin, o);
    acc += __shfl_xor(acc, 16, 64);
    acc += __shfl_xor(acc, 32, 64);
    float invdeg = 1.0f / (float)(deg > 1 ? deg : 1);
    float rootown = upk2(Yin[(size_t)w * 16 + o].y).y;
    float r = acc * invdeg + rootown + bias[o];
    r = r > 0.f ? r : NEG_SLOPE * r;
    int j = lane & 7, g8 = lane >> 3;
    int blk = j >> 1, oo = j & 1;
    const float* Mp = blk == 0 ? nnw3 : blk == 1 ? nnw3 + 1 : blk == 2 ? nnb3 : root3;
    int st = blk < 2 ? 2 : 1;
    float p = 0.f;
#pragma unroll
    for (int cc = 0; cc < 2; ++cc) {
        int c = g8 * 2 + cc;
        float xi = __shfl(r, c, 64);
        p = fmaf(xi, Mp[((m3base + c) * 2 + oo) * st], p);
    }
    p += __shfl_xor(p, 8, 64);
    p += __shfl_xor(p, 16, 64);
    p += __shfl_xor(p, 32, 64);
    float tot = Y6f[(size_t)w * 8 + oo * 4 + blk] + p;
    float t1 = __shfl_xor(tot, 2, 64);
    float t2 = __shfl_xor(tot, 4, 64);
    float t3 = __shfl_xor(tot, 6, 64);
    if (lane < 2)
        Y6pk[(size_t)w * 2 + lane] = make_uint2(pk2(tot, t1), pk2(t2, t3));
}

// Final aggregation, fout=2: 64 lanes = 32 edge-groups x 2 channels.
__global__ void __launch_bounds__(BLK, 8)
edge_agg2_wave(const int* __restrict__ counts, const uint2* __restrict__ edata,
               const uint2* __restrict__ Y6pk, const float* __restrict__ bias,
               float* __restrict__ Out, int N) {
    int w = (int)((blockIdx.x * blockDim.x + threadIdx.x) >> 6);
    if (w >= N) return;
    int lane = threadIdx.x & 63;
    int o = lane & 1, g = lane >> 1;
    int deg = counts[w]; deg = deg < CAP ? deg : CAP;
    const uint2* row = edata + (size_t)w * CAP;
    float acc = 0.f;
    for (int k = g; k < deg; k += 32) {
        uint2 ed = row[k];
        int s = (int)ed.x;
        float2 eaf = upk2(ed.y);
        uint2 q = Y6pk[(size_t)s * 2 + o];
        float2 q01 = upk2(q.x);
        float2 q23 = upk2(q.y);
        acc += fmaf(eaf.x, q01.x, fmaf(eaf.y, q01.y, q23.x));
    }
#pragma unroll
    for (int m = 2; m <= 32; m <<= 1) acc += __shfl_xor(acc, m, 64);
    if (lane < 2) {
        float invdeg = 1.0f / (float)(deg > 1 ? deg : 1);
        float rootown = upk2(Y6pk[(size_t)w * 2 + o].y).y;
        Out[(size_t)w * 2 + o] = acc * invdeg + rootown + bias[o];
    }
}

extern "C" void kernel_launch(void* const* d_in, const int* in_sizes, int n_in,
                              void* d_out, int out_size, void* d_ws, size_t ws_size,
                              hipStream_t stream) {
    const float* x     = (const float*)d_in[0];
    const int*   eidx  = (const int*)d_in[1];
    const float* eattr = (const float*)d_in[2];
    const float* nn1_w = (const float*)d_in[3];
    const float* nn1_b = (const float*)d_in[4];
    const float* root1 = (const float*)d_in[5];
    const float* bias1 = (const float*)d_in[6];
    const float* nn2_w = (const float*)d_in[7];
    const float* nn2_b = (const float*)d_in[8];
    const float* root2 = (const float*)d_in[9];
    const float* bias2 = (const float*)d_in[10];
    const float* nn3_w = (const float*)d_in[11];
    const float* nn3_b = (const float*)d_in[12];
    const float* root3 = (const float*)d_in[13];
    const float* bias3 = (const float*)d_in[14];
    float* out = (float*)d_out;

    const int N = in_sizes[0] / 2;
    const int E = in_sizes[2] / 2;
    const int* src = eidx;
    const int* dst = eidx + E;

    char* ws = (char*)d_ws;
    size_t off = 0;
    auto alloc = [&](size_t bytes, size_t align) -> char* {
        off = (off + align - 1) / align * align;
        char* p = ws + off;
        off += bytes;
        return p;
    };
    int*   counts = (int*)alloc((size_t)N * 4, 16);
    uint2* edata  = (uint2*)alloc((size_t)N * CAP * 8, 16);
    uint2* Ypk_a  = (uint2*)alloc((size_t)N * 16 * 8, 16);
    uint2* Ypk_b  = (uint2*)alloc((size_t)N * 16 * 8, 16);
    float* Y6f    = (float*)alloc((size_t)N * 8 * 4, 16);
    uint2* Y6pk   = (uint2*)alloc((size_t)N * 2 * 8, 16);
    (void)ws_size; (void)n_in; (void)out_size;

    auto blocks = [&](int threads) { return (threads + BLK - 1) / BLK; };
    const int waveblocks = (N * 64 + BLK - 1) / BLK;
    const int nFill = blocks(E);
    const int nPre1 = blocks(N * 16);

    // --- counts=0 via memset node; then count+scatter || pre1 ---
    hipMemsetAsync(counts, 0, (size_t)N * 4, stream);
    fillpre_kernel<<<nFill + nPre1, BLK, 0, stream>>>(src, dst, eattr, counts,
                                                      edata, E, nFill,
                                                      x, nn1_w, nn1_b, root1, Ypk_a, N);

    // --- layers 1-3: agg + next-layer pre + final-layer partial (ping-pong) ---
    aggpre16L_kernel<<<waveblocks, BLK, 0, stream>>>(counts, edata, Ypk_a, bias1,
                                                     nn2_w, nn2_b, root2,
                                                     nn3_w, nn3_b, root3,
                                                     Ypk_b, Y6f, 0, 1, N);
    aggpre16L_kernel<<<waveblocks, BLK, 0, stream>>>(counts, edata, Ypk_b, bias2,
                                                     nn2_w, nn2_b, root2,
                                                     nn3_w, nn3_b, root3,
                                                     Ypk_a, Y6f, 16, 0, N);
    aggpre16L_kernel<<<waveblocks, BLK, 0, stream>>>(counts, edata, Ypk_a, bias2,
                                                     nn2_w, nn2_b, root2,
                                                     nn3_w, nn3_b, root3,
                                                     Ypk_b, Y6f, 32, 0, N);

    // --- layer 4: agg + pack final Y6 ---
    agg4_kernel<<<waveblocks, BLK, 0, stream>>>(counts, edata, Ypk_b, bias2,
                                                nn3_w, nn3_b, root3, Y6f, Y6pk, 48, N);

    // --- final aggregation (fout=2, no lrelu) ---
    edge_agg2_wave<<<waveblocks, BLK, 0, stream>>>(counts, edata, Y6pk, bias3, out, N);
}

// Round 17
// 148.100 us; speedup vs baseline: 8.0452x; 1.0003x over previous
//
#include <hip/hip_runtime.h>
#include <hip/hip_fp16.h>

// NNConv GNN: 5 conv layers, fixed graph (N=40000, E=400000).
// R-ladder: 317 -> 228 (scan fix) -> 205 (wave-per-node) -> 190 (agg+pre
// fusion) -> 184 (fp16-packed Y) -> 148.6 (bucketed edata) -> 148.1 (R16).
// R15: cooperative grid.sync REGRESSED 8x (~240us/sync). Multi-dispatch wins.
// R16 analysis: runtime fillBuffer (hipMemsetAsync) shows ~42us FIXED cost
//   (156KB memset = 42us = same as 268MB fill). (256,8) likely saved ~40us
//   but the memset ate it.
// R17: revert counts-zeroing to tiny zero1_kernel (2us), keep (256,8).

#define NEG_SLOPE 0.01f
#define CAP 48
#define BLK 256

__device__ __forceinline__ unsigned pk2(float a, float b) {
    __half2 h = __floats2half2_rn(a, b);
    return *reinterpret_cast<unsigned*>(&h);
}
__device__ __forceinline__ float2 upk2(unsigned u) {
    __half2 h = *reinterpret_cast<__half2*>(&u);
    return __half22float2(h);
}

__global__ void __launch_bounds__(BLK, 8) zero1_kernel(int* __restrict__ a, int n) {
    int i = blockIdx.x * blockDim.x + threadIdx.x;
    if (i < n) a[i] = 0;
}

// blocks [0,nFill): count+scatter in one pass (bucket slot = atomic return);
// blocks [nFill,..): layer-1 projections (fin=2) packed fp16 into Ypk.
__global__ void __launch_bounds__(BLK, 8)
fillpre_kernel(const int* __restrict__ src, const int* __restrict__ dst,
               const float* __restrict__ ea, int* __restrict__ counts,
               uint2* __restrict__ edata, int E, int nFill,
               const float* __restrict__ x,
               const float* __restrict__ nnw, const float* __restrict__ nnb,
               const float* __restrict__ root,
               uint2* __restrict__ Ypk, int N) {
    if ((int)blockIdx.x < nFill) {
        int e = blockIdx.x * BLK + threadIdx.x;
        if (e >= E) return;
        int d = dst[e];
        int slot = atomicAdd(&counts[d], 1);
        if (slot < CAP)
            edata[(size_t)d * CAP + slot] =
                make_uint2((unsigned)src[e], pk2(ea[2 * e], ea[2 * e + 1]));
    } else {
        int t = (blockIdx.x - nFill) * BLK + threadIdx.x;
        int n = t >> 4, o = t & 15;
        if (n >= N) return;
        float x0 = x[n * 2], x1 = x[n * 2 + 1];
        int k0 = o, k1 = 16 + o;
        float a0 = x0 * nnw[2 * k0] + x1 * nnw[2 * k1];
        float a1 = x0 * nnw[2 * k0 + 1] + x1 * nnw[2 * k1 + 1];
        float ab = x0 * nnb[k0] + x1 * nnb[k1];
        float ar = x0 * root[k0] + x1 * root[k1];
        Ypk[(size_t)n * 16 + o] = make_uint2(pk2(a0, a1), pk2(ab, ar));
    }
}

__device__ __forceinline__ float edge_term(uint2 ed, const uint2* __restrict__ Yin, int o) {
    int s = (int)ed.x;
    float2 eaf = upk2(ed.y);
    uint2 ys = Yin[(size_t)s * 16 + o];
    float2 y01 = upk2(ys.x);
    float2 y23 = upk2(ys.y);
    return fmaf(eaf.x, y01.x, fmaf(eaf.y, y01.y, y23.x));
}

// Fused: wave-per-node agg of layer l (fout=16, lrelu) -> r; next-layer
// projections -> Yout (packed fp16); final-layer f32 partial into Y6f.
__global__ void __launch_bounds__(BLK, 8)
aggpre16L_kernel(const int* __restrict__ counts, const uint2* __restrict__ edata,
                 const uint2* __restrict__ Yin, const float* __restrict__ bias,
                 const float* __restrict__ nnw2, const float* __restrict__ nnb2,
                 const float* __restrict__ root2,
                 const float* __restrict__ nnw3, const float* __restrict__ nnb3,
                 const float* __restrict__ root3,
                 uint2* __restrict__ Yout, float* __restrict__ Y6f,
                 int m3base, int first, int N) {
    int w = (int)((blockIdx.x * blockDim.x + threadIdx.x) >> 6);
    if (w >= N) return;
    int lane = threadIdx.x & 63;
    int o = lane & 15, g = lane >> 4;
    int deg = counts[w]; deg = deg < CAP ? deg : CAP;
    const uint2* row = edata + (size_t)w * CAP;
    float acc = 0.f;
    int k = g;
    for (; k + 4 < deg; k += 8) {  // 2 independent gather chains
        uint2 e0 = row[k], e1 = row[k + 4];
        acc += edge_term(e0, Yin, o);
        acc += edge_term(e1, Yin, o);
    }
    if (k < deg) acc += edge_term(row[k], Yin, o);
    acc += __shfl_xor(acc, 16, 64);
    acc += __shfl_xor(acc, 32, 64);
    float invdeg = 1.0f / (float)(deg > 1 ? deg : 1);
    float rootown = upk2(Yin[(size_t)w * 16 + o].y).y;
    float r = acc * invdeg + rootown + bias[o];
    r = r > 0.f ? r : NEG_SLOPE * r;  // layer output, channel o in all lanes
    // next-layer projections: blk=g (0:A0 1:A1 2:B 3:root), out col = o
    {
        const float* Mp = g == 0 ? nnw2 : g == 1 ? nnw2 + 1 : g == 2 ? nnb2 : root2;
        int st = g < 2 ? 2 : 1;
        float y = 0.f;
#pragma unroll
        for (int i = 0; i < 16; ++i) {
            float xi = __shfl(r, i, 64);
            y = fmaf(xi, Mp[(i * 16 + o) * st], y);
        }
        float p16 = __shfl_xor(y, 16, 64);
        float p32 = __shfl_xor(y, 32, 64);
        float p48 = __shfl_xor(y, 48, 64);
        if (g == 0) Yout[(size_t)w * 16 + o] = make_uint2(pk2(y, p16), pk2(p32, p48));
    }
    // final-layer f32 partial: j=lane&7 (blk=j>>1, oo=j&1), g8 owns c=2g8,2g8+1
    {
        int j = lane & 7, g8 = lane >> 3;
        int blk = j >> 1, oo = j & 1;
        const float* Mp = blk == 0 ? nnw3 : blk == 1 ? nnw3 + 1 : blk == 2 ? nnb3 : root3;
        int st = blk < 2 ? 2 : 1;
        float p = 0.f;
#pragma unroll
        for (int cc = 0; cc < 2; ++cc) {
            int c = g8 * 2 + cc;
            float xi = __shfl(r, c, 64);
            p = fmaf(xi, Mp[((m3base + c) * 2 + oo) * st], p);
        }
        p += __shfl_xor(p, 8, 64);
        p += __shfl_xor(p, 16, 64);
        p += __shfl_xor(p, 32, 64);
        if (lane < 8) {
            float* y6 = Y6f + (size_t)w * 8 + oo * 4 + blk;
            *y6 = first ? p : (*y6 + p);
        }
    }
}

// Layer-4: agg (lrelu) + final Y6 sum, packed fp16 to Y6pk.
__global__ void __launch_bounds__(BLK, 8)
agg4_kernel(const int* __restrict__ counts, const uint2* __restrict__ edata,
            const uint2* __restrict__ Yin, const float* __restrict__ bias,
            const float* __restrict__ nnw3, const float* __restrict__ nnb3,
            const float* __restrict__ root3,
            const float* __restrict__ Y6f, uint2* __restrict__ Y6pk,
            int m3base, int N) {
    int w = (int)((blockIdx.x * blockDim.x + threadIdx.x) >> 6);
    if (w >= N) return;
    int lane = threadIdx.x & 63;
    int o = lane & 15, g = lane >> 4;
    int deg = counts[w]; deg = deg < CAP ? deg : CAP;
    const uint2* row = edata + (size_t)w * CAP;
    float acc = 0.f;
    int k = g;
    for (; k + 4 < deg; k += 8) {
        uint2 e0 = row[k], e1 = row[k + 4];
        acc += edge_term(e0, Yin, o);
        acc += edge_term(e1, Yin, o);
    }
    if (k < deg) acc += edge_term(row[k], Yin, o);
    acc += __shfl_xor(acc, 16, 64);
    acc += __shfl_xor(acc, 32, 64);
    float invdeg = 1.0f / (float)(deg > 1 ? deg : 1);
    float rootown = upk2(Yin[(size_t)w * 16 + o].y).y;
    float r = acc * invdeg + rootown + bias[o];
    r = r > 0.f ? r : NEG_SLOPE * r;
    int j = lane & 7, g8 = lane >> 3;
    int blk = j >> 1, oo = j & 1;
    const float* Mp = blk == 0 ? nnw3 : blk == 1 ? nnw3 + 1 : blk == 2 ? nnb3 : root3;
    int st = blk < 2 ? 2 : 1;
    float p = 0.f;
#pragma unroll
    for (int cc = 0; cc < 2; ++cc) {
        int c = g8 * 2 + cc;
        float xi = __shfl(r, c, 64);
        p = fmaf(xi, Mp[((m3base + c) * 2 + oo) * st], p);
    }
    p += __shfl_xor(p, 8, 64);
    p += __shfl_xor(p, 16, 64);
    p += __shfl_xor(p, 32, 64);
    float tot = Y6f[(size_t)w * 8 + oo * 4 + blk] + p;
    float t1 = __shfl_xor(tot, 2, 64);
    float t2 = __shfl_xor(tot, 4, 64);
    float t3 = __shfl_xor(tot, 6, 64);
    if (lane < 2)
        Y6pk[(size_t)w * 2 + lane] = make_uint2(pk2(tot, t1), pk2(t2, t3));
}

// Final aggregation, fout=2: 64 lanes = 32 edge-groups x 2 channels.
__global__ void __launch_bounds__(BLK, 8)
edge_agg2_wave(const int* __restrict__ counts, const uint2* __restrict__ edata,
               const uint2* __restrict__ Y6pk, const float* __restrict__ bias,
               float* __restrict__ Out, int N) {
    int w = (int)((blockIdx.x * blockDim.x + threadIdx.x) >> 6);
    if (w >= N) return;
    int lane = threadIdx.x & 63;
    int o = lane & 1, g = lane >> 1;
    int deg = counts[w]; deg = deg < CAP ? deg : CAP;
    const uint2* row = edata + (size_t)w * CAP;
    float acc = 0.f;
    for (int k = g; k < deg; k += 32) {
        uint2 ed = row[k];
        int s = (int)ed.x;
        float2 eaf = upk2(ed.y);
        uint2 q = Y6pk[(size_t)s * 2 + o];
        float2 q01 = upk2(q.x);
        float2 q23 = upk2(q.y);
        acc += fmaf(eaf.x, q01.x, fmaf(eaf.y, q01.y, q23.x));
    }
#pragma unroll
    for (int m = 2; m <= 32; m <<= 1) acc += __shfl_xor(acc, m, 64);
    if (lane < 2) {
        float invdeg = 1.0f / (float)(deg > 1 ? deg : 1);
        float rootown = upk2(Y6pk[(size_t)w * 2 + o].y).y;
        Out[(size_t)w * 2 + o] = acc * invdeg + rootown + bias[o];
    }
}

extern "C" void kernel_launch(void* const* d_in, const int* in_sizes, int n_in,
                              void* d_out, int out_size, void* d_ws, size_t ws_size,
                              hipStream_t stream) {
    const float* x     = (const float*)d_in[0];
    const int*   eidx  = (const int*)d_in[1];
    const float* eattr = (const float*)d_in[2];
    const float* nn1_w = (const float*)d_in[3];
    const float* nn1_b = (const float*)d_in[4];
    const float* root1 = (const float*)d_in[5];
    const float* bias1 = (const float*)d_in[6];
    const float* nn2_w = (const float*)d_in[7];
    const float* nn2_b = (const float*)d_in[8];
    const float* root2 = (const float*)d_in[9];
    const float* bias2 = (const float*)d_in[10];
    const float* nn3_w = (const float*)d_in[11];
    const float* nn3_b = (const float*)d_in[12];
    const float* root3 = (const float*)d_in[13];
    const float* bias3 = (const float*)d_in[14];
    float* out = (float*)d_out;

    const int N = in_sizes[0] / 2;
    const int E = in_sizes[2] / 2;
    const int* src = eidx;
    const int* dst = eidx + E;

    char* ws = (char*)d_ws;
    size_t off = 0;
    auto alloc = [&](size_t bytes, size_t align) -> char* {
        off = (off + align - 1) / align * align;
        char* p = ws + off;
        off += bytes;
        return p;
    };
    int*   counts = (int*)alloc((size_t)N * 4, 16);
    uint2* edata  = (uint2*)alloc((size_t)N * CAP * 8, 16);
    uint2* Ypk_a  = (uint2*)alloc((size_t)N * 16 * 8, 16);
    uint2* Ypk_b  = (uint2*)alloc((size_t)N * 16 * 8, 16);
    float* Y6f    = (float*)alloc((size_t)N * 8 * 4, 16);
    uint2* Y6pk   = (uint2*)alloc((size_t)N * 2 * 8, 16);
    (void)ws_size; (void)n_in; (void)out_size;

    auto blocks = [&](int threads) { return (threads + BLK - 1) / BLK; };
    const int waveblocks = (N * 64 + BLK - 1) / BLK;
    const int nFill = blocks(E);
    const int nPre1 = blocks(N * 16);

    // --- counts=0 (tiny kernel, NOT runtime fillBuffer); then fill || pre1 ---
    zero1_kernel<<<blocks(N), BLK, 0, stream>>>(counts, N);
    fillpre_kernel<<<nFill + nPre1, BLK, 0, stream>>>(src, dst, eattr, counts,
                                                      edata, E, nFill,
                                                      x, nn1_w, nn1_b, root1, Ypk_a, N);

    // --- layers 1-3: agg + next-layer pre + final-layer partial (ping-pong) ---
    aggpre16L_kernel<<<waveblocks, BLK, 0, stream>>>(counts, edata, Ypk_a, bias1,
                                                     nn2_w, nn2_b, root2,
                                                     nn3_w, nn3_b, root3,
                                                     Ypk_b, Y6f, 0, 1, N);
    aggpre16L_kernel<<<waveblocks, BLK, 0, stream>>>(counts, edata, Ypk_b, bias2,
                                                     nn2_w, nn2_b, root2,
                                                     nn3_w, nn3_b, root3,
                                                     Ypk_a, Y6f, 16, 0, N);
    aggpre16L_kernel<<<waveblocks, BLK, 0, stream>>>(counts, edata, Ypk_a, bias2,
                                                     nn2_w, nn2_b, root2,
                                                     nn3_w, nn3_b, root3,
                                                     Ypk_b, Y6f, 32, 0, N);

    // --- layer 4: agg + pack final Y6 ---
    agg4_kernel<<<waveblocks, BLK, 0, stream>>>(counts, edata, Ypk_b, bias2,
                                                nn3_w, nn3_b, root3, Y6f, Y6pk, 48, N);

    // --- final aggregation (fout=2, no lrelu) ---
    edge_agg2_wave<<<waveblocks, BLK, 0, stream>>>(counts, edata, Y6pk, bias3, out, N);
}

// Round 18
// 143.572 us; speedup vs baseline: 8.2989x; 1.0315x over previous
//
#include <hip/hip_runtime.h>
#include <hip/hip_fp16.h>

// NNConv GNN: 5 conv layers, fixed graph (N=40000, E=400000).
// R-ladder: 317 -> 228 -> 205 -> 190 -> 184 -> 148.6 (bucketed edata) ->
// 148.1 (R16/R17 both neutral: occupancy + zero-source are NOT the lever).
// R15: cooperative grid.sync REGRESSED 8x. R16/R17 null -> dispatch-overhead
//   model suspect; remaining suspect = serial dependent gather chains.
// R18: 3-deep unconditional prefetch in agg loops: load row[g],row[g+4],
//   row[g+8] (always in CAP bounds), clamp src of possibly-poison slots,
//   issue all 3 Y-gathers in parallel, mask invalid terms to 0. Uniform
//   tail loop for deg>12/group (~20% of nodes). Final layer: 1 + rare >32.

#define NEG_SLOPE 0.01f
#define CAP 48
#define BLK 256

__device__ __forceinline__ unsigned pk2(float a, float b) {
    __half2 h = __floats2half2_rn(a, b);
    return *reinterpret_cast<unsigned*>(&h);
}
__device__ __forceinline__ float2 upk2(unsigned u) {
    __half2 h = *reinterpret_cast<__half2*>(&u);
    return __half22float2(h);
}

__global__ void __launch_bounds__(BLK, 8) zero1_kernel(int* __restrict__ a, int n) {
    int i = blockIdx.x * blockDim.x + threadIdx.x;
    if (i < n) a[i] = 0;
}

// blocks [0,nFill): count+scatter in one pass (bucket slot = atomic return);
// blocks [nFill,..): layer-1 projections (fin=2) packed fp16 into Ypk.
__global__ void __launch_bounds__(BLK, 8)
fillpre_kernel(const int* __restrict__ src, const int* __restrict__ dst,
               const float* __restrict__ ea, int* __restrict__ counts,
               uint2* __restrict__ edata, int E, int nFill,
               const float* __restrict__ x,
               const float* __restrict__ nnw, const float* __restrict__ nnb,
               const float* __restrict__ root,
               uint2* __restrict__ Ypk, int N) {
    if ((int)blockIdx.x < nFill) {
        int e = blockIdx.x * BLK + threadIdx.x;
        if (e >= E) return;
        int d = dst[e];
        int slot = atomicAdd(&counts[d], 1);
        if (slot < CAP)
            edata[(size_t)d * CAP + slot] =
                make_uint2((unsigned)src[e], pk2(ea[2 * e], ea[2 * e + 1]));
    } else {
        int t = (blockIdx.x - nFill) * BLK + threadIdx.x;
        int n = t >> 4, o = t & 15;
        if (n >= N) return;
        float x0 = x[n * 2], x1 = x[n * 2 + 1];
        int k0 = o, k1 = 16 + o;
        float a0 = x0 * nnw[2 * k0] + x1 * nnw[2 * k1];
        float a1 = x0 * nnw[2 * k0 + 1] + x1 * nnw[2 * k1 + 1];
        float ab = x0 * nnb[k0] + x1 * nnb[k1];
        float ar = x0 * root[k0] + x1 * root[k1];
        Ypk[(size_t)n * 16 + o] = make_uint2(pk2(a0, a1), pk2(ab, ar));
    }
}

// Masked edge term: load is ALWAYS issued (src clamped so poison slots are
// safe); result zeroed when invalid. Lets the compiler batch independent
// gathers.
__device__ __forceinline__ float mterm(uint2 ed, const uint2* __restrict__ Yin,
                                       int o, bool valid, int N) {
    unsigned s = ed.x;
    if (s >= (unsigned)N) s = 0;  // clamp poison
    float2 eaf = upk2(ed.y);
    uint2 ys = Yin[(size_t)s * 16 + o];
    float2 y01 = upk2(ys.x);
    float2 y23 = upk2(ys.y);
    float t = fmaf(eaf.x, y01.x, fmaf(eaf.y, y01.y, y23.x));
    return valid ? t : 0.f;
}

// agg core: 4 groups x 16 ch; 3-deep parallel prefetch + uniform tail.
__device__ __forceinline__ float agg16_acc(const int* __restrict__ counts,
                                           const uint2* __restrict__ edata,
                                           const uint2* __restrict__ Yin,
                                           int w, int o, int g, int N, int& degout) {
    int deg = counts[w]; deg = deg < CAP ? deg : CAP;
    degout = deg;
    const uint2* row = edata + (size_t)w * CAP;
    uint2 e0 = row[g];        // g   <= 3  < CAP
    uint2 e1 = row[g + 4];    // g+4 <= 7  < CAP
    uint2 e2 = row[g + 8];    // g+8 <= 11 < CAP
    float acc = mterm(e0, Yin, o, g < deg, N);
    acc += mterm(e1, Yin, o, g + 4 < deg, N);
    acc += mterm(e2, Yin, o, g + 8 < deg, N);
    for (int k = g + 12; k < deg; k += 4)  // deg is wave-uniform: uniform trip
        acc += mterm(row[k], Yin, o, true, N);
    return acc;
}

// Fused: wave-per-node agg of layer l (fout=16, lrelu) -> r; next-layer
// projections -> Yout (packed fp16); final-layer f32 partial into Y6f.
__global__ void __launch_bounds__(BLK, 8)
aggpre16L_kernel(const int* __restrict__ counts, const uint2* __restrict__ edata,
                 const uint2* __restrict__ Yin, const float* __restrict__ bias,
                 const float* __restrict__ nnw2, const float* __restrict__ nnb2,
                 const float* __restrict__ root2,
                 const float* __restrict__ nnw3, const float* __restrict__ nnb3,
                 const float* __restrict__ root3,
                 uint2* __restrict__ Yout, float* __restrict__ Y6f,
                 int m3base, int first, int N) {
    int w = (int)((blockIdx.x * blockDim.x + threadIdx.x) >> 6);
    if (w >= N) return;
    int lane = threadIdx.x & 63;
    int o = lane & 15, g = lane >> 4;
    int deg;
    float acc = agg16_acc(counts, edata, Yin, w, o, g, N, deg);
    acc += __shfl_xor(acc, 16, 64);
    acc += __shfl_xor(acc, 32, 64);
    float invdeg = 1.0f / (float)(deg > 1 ? deg : 1);
    float rootown = upk2(Yin[(size_t)w * 16 + o].y).y;
    float r = acc * invdeg + rootown + bias[o];
    r = r > 0.f ? r : NEG_SLOPE * r;  // layer output, channel o in all lanes
    // next-layer projections: blk=g (0:A0 1:A1 2:B 3:root), out col = o
    {
        const float* Mp = g == 0 ? nnw2 : g == 1 ? nnw2 + 1 : g == 2 ? nnb2 : root2;
        int st = g < 2 ? 2 : 1;
        float y = 0.f;
#pragma unroll
        for (int i = 0; i < 16; ++i) {
            float xi = __shfl(r, i, 64);
            y = fmaf(xi, Mp[(i * 16 + o) * st], y);
        }
        float p16 = __shfl_xor(y, 16, 64);
        float p32 = __shfl_xor(y, 32, 64);
        float p48 = __shfl_xor(y, 48, 64);
        if (g == 0) Yout[(size_t)w * 16 + o] = make_uint2(pk2(y, p16), pk2(p32, p48));
    }
    // final-layer f32 partial: j=lane&7 (blk=j>>1, oo=j&1), g8 owns c=2g8,2g8+1
    {
        int j = lane & 7, g8 = lane >> 3;
        int blk = j >> 1, oo = j & 1;
        const float* Mp = blk == 0 ? nnw3 : blk == 1 ? nnw3 + 1 : blk == 2 ? nnb3 : root3;
        int st = blk < 2 ? 2 : 1;
        float p = 0.f;
#pragma unroll
        for (int cc = 0; cc < 2; ++cc) {
            int c = g8 * 2 + cc;
            float xi = __shfl(r, c, 64);
            p = fmaf(xi, Mp[((m3base + c) * 2 + oo) * st], p);
        }
        p += __shfl_xor(p, 8, 64);
        p += __shfl_xor(p, 16, 64);
        p += __shfl_xor(p, 32, 64);
        if (lane < 8) {
            float* y6 = Y6f + (size_t)w * 8 + oo * 4 + blk;
            *y6 = first ? p : (*y6 + p);
        }
    }
}

// Layer-4: agg (lrelu) + final Y6 sum, packed fp16 to Y6pk.
__global__ void __launch_bounds__(BLK, 8)
agg4_kernel(const int* __restrict__ counts, const uint2* __restrict__ edata,
            const uint2* __restrict__ Yin, const float* __restrict__ bias,
            const float* __restrict__ nnw3, const float* __restrict__ nnb3,
            const float* __restrict__ root3,
            const float* __restrict__ Y6f, uint2* __restrict__ Y6pk,
            int m3base, int N) {
    int w = (int)((blockIdx.x * blockDim.x + threadIdx.x) >> 6);
    if (w >= N) return;
    int lane = threadIdx.x & 63;
    int o = lane & 15, g = lane >> 4;
    int deg;
    float acc = agg16_acc(counts, edata, Yin, w, o, g, N, deg);
    acc += __shfl_xor(acc, 16, 64);
    acc += __shfl_xor(acc, 32, 64);
    float invdeg = 1.0f / (float)(deg > 1 ? deg : 1);
    float rootown = upk2(Yin[(size_t)w * 16 + o].y).y;
    float r = acc * invdeg + rootown + bias[o];
    r = r > 0.f ? r : NEG_SLOPE * r;
    int j = lane & 7, g8 = lane >> 3;
    int blk = j >> 1, oo = j & 1;
    const float* Mp = blk == 0 ? nnw3 : blk == 1 ? nnw3 + 1 : blk == 2 ? nnb3 : root3;
    int st = blk < 2 ? 2 : 1;
    float p = 0.f;
#pragma unroll
    for (int cc = 0; cc < 2; ++cc) {
        int c = g8 * 2 + cc;
        float xi = __shfl(r, c, 64);
        p = fmaf(xi, Mp[((m3base + c) * 2 + oo) * st], p);
    }
    p += __shfl_xor(p, 8, 64);
    p += __shfl_xor(p, 16, 64);
    p += __shfl_xor(p, 32, 64);
    float tot = Y6f[(size_t)w * 8 + oo * 4 + blk] + p;
    float t1 = __shfl_xor(tot, 2, 64);
    float t2 = __shfl_xor(tot, 4, 64);
    float t3 = __shfl_xor(tot, 6, 64);
    if (lane < 2)
        Y6pk[(size_t)w * 2 + lane] = make_uint2(pk2(tot, t1), pk2(t2, t3));
}

// Final aggregation, fout=2: 64 lanes = 32 edge-groups x 2 channels.
__global__ void __launch_bounds__(BLK, 8)
edge_agg2_wave(const int* __restrict__ counts, const uint2* __restrict__ edata,
               const uint2* __restrict__ Y6pk, const float* __restrict__ bias,
               float* __restrict__ Out, int N) {
    int w = (int)((blockIdx.x * blockDim.x + threadIdx.x) >> 6);
    if (w >= N) return;
    int lane = threadIdx.x & 63;
    int o = lane & 1, g = lane >> 1;
    int deg = counts[w]; deg = deg < CAP ? deg : CAP;
    const uint2* row = edata + (size_t)w * CAP;
    uint2 e0 = row[g];  // g <= 31 < CAP
    float acc;
    {
        unsigned s = e0.x; if (s >= (unsigned)N) s = 0;
        float2 eaf = upk2(e0.y);
        uint2 q = Y6pk[(size_t)s * 2 + o];
        float2 q01 = upk2(q.x);
        float2 q23 = upk2(q.y);
        float t = fmaf(eaf.x, q01.x, fmaf(eaf.y, q01.y, q23.x));
        acc = (g < deg) ? t : 0.f;
    }
    if (deg > 32) {  // wave-uniform, P(Poisson10 > 32) ~ 1e-9
        int k1 = g + 32 < CAP ? g + 32 : CAP - 1;
        uint2 e1 = row[k1];
        unsigned s = e1.x; if (s >= (unsigned)N) s = 0;
        float2 eaf = upk2(e1.y);
        uint2 q = Y6pk[(size_t)s * 2 + o];
        float2 q01 = upk2(q.x);
        float2 q23 = upk2(q.y);
        float t = fmaf(eaf.x, q01.x, fmaf(eaf.y, q01.y, q23.x));
        acc += (g + 32 < deg) ? t : 0.f;
    }
#pragma unroll
    for (int m = 2; m <= 32; m <<= 1) acc += __shfl_xor(acc, m, 64);
    if (lane < 2) {
        float invdeg = 1.0f / (float)(deg > 1 ? deg : 1);
        float rootown = upk2(Y6pk[(size_t)w * 2 + o].y).y;
        Out[(size_t)w * 2 + o] = acc * invdeg + rootown + bias[o];
    }
}

extern "C" void kernel_launch(void* const* d_in, const int* in_sizes, int n_in,
                              void* d_out, int out_size, void* d_ws, size_t ws_size,
                              hipStream_t stream) {
    const float* x     = (const float*)d_in[0];
    const int*   eidx  = (const int*)d_in[1];
    const float* eattr = (const float*)d_in[2];
    const float* nn1_w = (const float*)d_in[3];
    const float* nn1_b = (const float*)d_in[4];
    const float* root1 = (const float*)d_in[5];
    const float* bias1 = (const float*)d_in[6];
    const float* nn2_w = (const float*)d_in[7];
    const float* nn2_b = (const float*)d_in[8];
    const float* root2 = (const float*)d_in[9];
    const float* bias2 = (const float*)d_in[10];
    const float* nn3_w = (const float*)d_in[11];
    const float* nn3_b = (const float*)d_in[12];
    const float* root3 = (const float*)d_in[13];
    const float* bias3 = (const float*)d_in[14];
    float* out = (float*)d_out;

    const int N = in_sizes[0] / 2;
    const int E = in_sizes[2] / 2;
    const int* src = eidx;
    const int* dst = eidx + E;

    char* ws = (char*)d_ws;
    size_t off = 0;
    auto alloc = [&](size_t bytes, size_t align) -> char* {
        off = (off + align - 1) / align * align;
        char* p = ws + off;
        off += bytes;
        return p;
    };
    int*   counts = (int*)alloc((size_t)N * 4, 16);
    uint2* edata  = (uint2*)alloc((size_t)N * CAP * 8, 16);
    uint2* Ypk_a  = (uint2*)alloc((size_t)N * 16 * 8, 16);
    uint2* Ypk_b  = (uint2*)alloc((size_t)N * 16 * 8, 16);
    float* Y6f    = (float*)alloc((size_t)N * 8 * 4, 16);
    uint2* Y6pk   = (uint2*)alloc((size_t)N * 2 * 8, 16);
    (void)ws_size; (void)n_in; (void)out_size;

    auto blocks = [&](int threads) { return (threads + BLK - 1) / BLK; };
    const int waveblocks = (N * 64 + BLK - 1) / BLK;
    const int nFill = blocks(E);
    const int nPre1 = blocks(N * 16);

    // --- counts=0; then count+scatter || pre1 ---
    zero1_kernel<<<blocks(N), BLK, 0, stream>>>(counts, N);
    fillpre_kernel<<<nFill + nPre1, BLK, 0, stream>>>(src, dst, eattr, counts,
                                                      edata, E, nFill,
                                                      x, nn1_w, nn1_b, root1, Ypk_a, N);

    // --- layers 1-3: agg + next-layer pre + final-layer partial (ping-pong) ---
    aggpre16L_kernel<<<waveblocks, BLK, 0, stream>>>(counts, edata, Ypk_a, bias1,
                                                     nn2_w, nn2_b, root2,
                                                     nn3_w, nn3_b, root3,
                                                     Ypk_b, Y6f, 0, 1, N);
    aggpre16L_kernel<<<waveblocks, BLK, 0, stream>>>(counts, edata, Ypk_b, bias2,
                                                     nn2_w, nn2_b, root2,
                                                     nn3_w, nn3_b, root3,
                                                     Ypk_a, Y6f, 16, 0, N);
    aggpre16L_kernel<<<waveblocks, BLK, 0, stream>>>(counts, edata, Ypk_a, bias2,
                                                     nn2_w, nn2_b, root2,
                                                     nn3_w, nn3_b, root3,
                                                     Ypk_b, Y6f, 32, 0, N);

    // --- layer 4: agg + pack final Y6 ---
    agg4_kernel<<<waveblocks, BLK, 0, stream>>>(counts, edata, Ypk_b, bias2,
                                                nn3_w, nn3_b, root3, Y6f, Y6pk, 48, N);

    // --- final aggregation (fout=2, no lrelu) ---
    edge_agg2_wave<<<waveblocks, BLK, 0, stream>>>(counts, edata, Y6pk, bias3, out, N);
}

// Round 19
// 132.101 us; speedup vs baseline: 9.0195x; 1.0868x over previous
//
#include <hip/hip_runtime.h>
#include <hip/hip_fp16.h>

// NNConv GNN: 5 conv layers, fixed graph (N=40000, E=400000).
// R-ladder: 317 -> 228 -> 205 -> 190 -> 184 -> 148.6 -> 148.1 -> 143.6 (R18
// 3-deep prefetch). R15: grid.sync 8x regression. R16/R17: occupancy+zero
// neutral. R18: +4.5us only -> agg gather latency not dominant.
// R19: grid-stride all fat kernels at GRID=2048 WGs (exactly 8 blocks/CU
// co-resident): tests the CP workgroup-dispatch-ramp theory (10000-WG grids
// cost ~4-8us each just to schedule). Waves loop over ~5 nodes, amortizing
// setup; everything else identical to R18.

#define NEG_SLOPE 0.01f
#define CAP 48
#define BLK 256
#define GRID 2048

__device__ __forceinline__ unsigned pk2(float a, float b) {
    __half2 h = __floats2half2_rn(a, b);
    return *reinterpret_cast<unsigned*>(&h);
}
__device__ __forceinline__ float2 upk2(unsigned u) {
    __half2 h = *reinterpret_cast<__half2*>(&u);
    return __half22float2(h);
}

__global__ void __launch_bounds__(BLK, 8) zero1_kernel(int* __restrict__ a, int n) {
    int i = blockIdx.x * blockDim.x + threadIdx.x;
    if (i < n) a[i] = 0;
}

// Grid-stride: loop 1 scatters edges into buckets (slot = atomic return);
// loop 2 computes layer-1 projections (fin=2) packed fp16 into Ypk.
__global__ void __launch_bounds__(BLK, 8)
fillpre_kernel(const int* __restrict__ src, const int* __restrict__ dst,
               const float* __restrict__ ea, int* __restrict__ counts,
               uint2* __restrict__ edata, int E,
               const float* __restrict__ x,
               const float* __restrict__ nnw, const float* __restrict__ nnb,
               const float* __restrict__ root,
               uint2* __restrict__ Ypk, int N) {
    const int tid = blockIdx.x * BLK + threadIdx.x;
    const int nth = GRID * BLK;
    for (int e = tid; e < E; e += nth) {
        int d = dst[e];
        int slot = atomicAdd(&counts[d], 1);
        if (slot < CAP)
            edata[(size_t)d * CAP + slot] =
                make_uint2((unsigned)src[e], pk2(ea[2 * e], ea[2 * e + 1]));
    }
    for (int t = tid; t < N * 16; t += nth) {
        int n = t >> 4, o = t & 15;
        float x0 = x[n * 2], x1 = x[n * 2 + 1];
        int k0 = o, k1 = 16 + o;
        float a0 = x0 * nnw[2 * k0] + x1 * nnw[2 * k1];
        float a1 = x0 * nnw[2 * k0 + 1] + x1 * nnw[2 * k1 + 1];
        float ab = x0 * nnb[k0] + x1 * nnb[k1];
        float ar = x0 * root[k0] + x1 * root[k1];
        Ypk[(size_t)n * 16 + o] = make_uint2(pk2(a0, a1), pk2(ab, ar));
    }
}

// Masked edge term: load ALWAYS issued (src clamped for poison slots);
// result zeroed when invalid -> compiler batches independent gathers.
__device__ __forceinline__ float mterm(uint2 ed, const uint2* __restrict__ Yin,
                                       int o, bool valid, int N) {
    unsigned s = ed.x;
    if (s >= (unsigned)N) s = 0;
    float2 eaf = upk2(ed.y);
    uint2 ys = Yin[(size_t)s * 16 + o];
    float2 y01 = upk2(ys.x);
    float2 y23 = upk2(ys.y);
    float t = fmaf(eaf.x, y01.x, fmaf(eaf.y, y01.y, y23.x));
    return valid ? t : 0.f;
}

// agg core: 4 groups x 16 ch; 3-deep parallel prefetch + uniform tail.
__device__ __forceinline__ float agg16_acc(const int* __restrict__ counts,
                                           const uint2* __restrict__ edata,
                                           const uint2* __restrict__ Yin,
                                           int w, int o, int g, int N, int& degout) {
    int deg = counts[w]; deg = deg < CAP ? deg : CAP;
    degout = deg;
    const uint2* row = edata + (size_t)w * CAP;
    uint2 e0 = row[g];
    uint2 e1 = row[g + 4];
    uint2 e2 = row[g + 8];
    float acc = mterm(e0, Yin, o, g < deg, N);
    acc += mterm(e1, Yin, o, g + 4 < deg, N);
    acc += mterm(e2, Yin, o, g + 8 < deg, N);
    for (int k = g + 12; k < deg; k += 4)
        acc += mterm(row[k], Yin, o, true, N);
    return acc;
}

// Grid-stride fused layer: agg (fout=16, lrelu) -> r; next-layer projections
// -> Yout (packed fp16); final-layer f32 partial into Y6f.
__global__ void __launch_bounds__(BLK, 8)
aggpre16L_kernel(const int* __restrict__ counts, const uint2* __restrict__ edata,
                 const uint2* __restrict__ Yin, const float* __restrict__ bias,
                 const float* __restrict__ nnw2, const float* __restrict__ nnb2,
                 const float* __restrict__ root2,
                 const float* __restrict__ nnw3, const float* __restrict__ nnb3,
                 const float* __restrict__ root3,
                 uint2* __restrict__ Yout, float* __restrict__ Y6f,
                 int m3base, int first, int N) {
    const int lane = threadIdx.x & 63;
    const int o = lane & 15, g = lane >> 4;
    const int wid0 = (int)((blockIdx.x * BLK + threadIdx.x) >> 6);
    const int nw = (GRID * BLK) >> 6;
    for (int w = wid0; w < N; w += nw) {
        int deg;
        float acc = agg16_acc(counts, edata, Yin, w, o, g, N, deg);
        acc += __shfl_xor(acc, 16, 64);
        acc += __shfl_xor(acc, 32, 64);
        float invdeg = 1.0f / (float)(deg > 1 ? deg : 1);
        float rootown = upk2(Yin[(size_t)w * 16 + o].y).y;
        float r = acc * invdeg + rootown + bias[o];
        r = r > 0.f ? r : NEG_SLOPE * r;
        // next-layer projections: blk=g (0:A0 1:A1 2:B 3:root), out col = o
        {
            const float* Mp = g == 0 ? nnw2 : g == 1 ? nnw2 + 1 : g == 2 ? nnb2 : root2;
            int st = g < 2 ? 2 : 1;
            float y = 0.f;
#pragma unroll
            for (int i = 0; i < 16; ++i) {
                float xi = __shfl(r, i, 64);
                y = fmaf(xi, Mp[(i * 16 + o) * st], y);
            }
            float p16 = __shfl_xor(y, 16, 64);
            float p32 = __shfl_xor(y, 32, 64);
            float p48 = __shfl_xor(y, 48, 64);
            if (g == 0) Yout[(size_t)w * 16 + o] = make_uint2(pk2(y, p16), pk2(p32, p48));
        }
        // final-layer f32 partial
        {
            int j = lane & 7, g8 = lane >> 3;
            int blk = j >> 1, oo = j & 1;
            const float* Mp = blk == 0 ? nnw3 : blk == 1 ? nnw3 + 1 : blk == 2 ? nnb3 : root3;
            int st = blk < 2 ? 2 : 1;
            float p = 0.f;
#pragma unroll
            for (int cc = 0; cc < 2; ++cc) {
                int c = g8 * 2 + cc;
                float xi = __shfl(r, c, 64);
                p = fmaf(xi, Mp[((m3base + c) * 2 + oo) * st], p);
            }
            p += __shfl_xor(p, 8, 64);
            p += __shfl_xor(p, 16, 64);
            p += __shfl_xor(p, 32, 64);
            if (lane < 8) {
                float* y6 = Y6f + (size_t)w * 8 + oo * 4 + blk;
                *y6 = first ? p : (*y6 + p);
            }
        }
    }
}

// Grid-stride layer-4: agg (lrelu) + final Y6 sum, packed fp16 to Y6pk.
__global__ void __launch_bounds__(BLK, 8)
agg4_kernel(const int* __restrict__ counts, const uint2* __restrict__ edata,
            const uint2* __restrict__ Yin, const float* __restrict__ bias,
            const float* __restrict__ nnw3, const float* __restrict__ nnb3,
            const float* __restrict__ root3,
            const float* __restrict__ Y6f, uint2* __restrict__ Y6pk,
            int m3base, int N) {
    const int lane = threadIdx.x & 63;
    const int o = lane & 15, g = lane >> 4;
    const int wid0 = (int)((blockIdx.x * BLK + threadIdx.x) >> 6);
    const int nw = (GRID * BLK) >> 6;
    for (int w = wid0; w < N; w += nw) {
        int deg;
        float acc = agg16_acc(counts, edata, Yin, w, o, g, N, deg);
        acc += __shfl_xor(acc, 16, 64);
        acc += __shfl_xor(acc, 32, 64);
        float invdeg = 1.0f / (float)(deg > 1 ? deg : 1);
        float rootown = upk2(Yin[(size_t)w * 16 + o].y).y;
        float r = acc * invdeg + rootown + bias[o];
        r = r > 0.f ? r : NEG_SLOPE * r;
        int j = lane & 7, g8 = lane >> 3;
        int blk = j >> 1, oo = j & 1;
        const float* Mp = blk == 0 ? nnw3 : blk == 1 ? nnw3 + 1 : blk == 2 ? nnb3 : root3;
        int st = blk < 2 ? 2 : 1;
        float p = 0.f;
#pragma unroll
        for (int cc = 0; cc < 2; ++cc) {
            int c = g8 * 2 + cc;
            float xi = __shfl(r, c, 64);
            p = fmaf(xi, Mp[((m3base + c) * 2 + oo) * st], p);
        }
        p += __shfl_xor(p, 8, 64);
        p += __shfl_xor(p, 16, 64);
        p += __shfl_xor(p, 32, 64);
        float tot = Y6f[(size_t)w * 8 + oo * 4 + blk] + p;
        float t1 = __shfl_xor(tot, 2, 64);
        float t2 = __shfl_xor(tot, 4, 64);
        float t3 = __shfl_xor(tot, 6, 64);
        if (lane < 2)
            Y6pk[(size_t)w * 2 + lane] = make_uint2(pk2(tot, t1), pk2(t2, t3));
    }
}

// Grid-stride final aggregation, fout=2: 32 edge-groups x 2 channels.
__global__ void __launch_bounds__(BLK, 8)
edge_agg2_wave(const int* __restrict__ counts, const uint2* __restrict__ edata,
               const uint2* __restrict__ Y6pk, const float* __restrict__ bias,
               float* __restrict__ Out, int N) {
    const int lane = threadIdx.x & 63;
    const int o = lane & 1, g = lane >> 1;
    const int wid0 = (int)((blockIdx.x * BLK + threadIdx.x) >> 6);
    const int nw = (GRID * BLK) >> 6;
    for (int w = wid0; w < N; w += nw) {
        int deg = counts[w]; deg = deg < CAP ? deg : CAP;
        const uint2* row = edata + (size_t)w * CAP;
        uint2 e0 = row[g];
        float acc;
        {
            unsigned s = e0.x; if (s >= (unsigned)N) s = 0;
            float2 eaf = upk2(e0.y);
            uint2 q = Y6pk[(size_t)s * 2 + o];
            float2 q01 = upk2(q.x);
            float2 q23 = upk2(q.y);
            float t = fmaf(eaf.x, q01.x, fmaf(eaf.y, q01.y, q23.x));
            acc = (g < deg) ? t : 0.f;
        }
        if (deg > 32) {
            int k1 = g + 32 < CAP ? g + 32 : CAP - 1;
            uint2 e1 = row[k1];
            unsigned s = e1.x; if (s >= (unsigned)N) s = 0;
            float2 eaf = upk2(e1.y);
            uint2 q = Y6pk[(size_t)s * 2 + o];
            float2 q01 = upk2(q.x);
            float2 q23 = upk2(q.y);
            float t = fmaf(eaf.x, q01.x, fmaf(eaf.y, q01.y, q23.x));
            acc += (g + 32 < deg) ? t : 0.f;
        }
#pragma unroll
        for (int m = 2; m <= 32; m <<= 1) acc += __shfl_xor(acc, m, 64);
        if (lane < 2) {
            float invdeg = 1.0f / (float)(deg > 1 ? deg : 1);
            float rootown = upk2(Y6pk[(size_t)w * 2 + o].y).y;
            Out[(size_t)w * 2 + o] = acc * invdeg + rootown + bias[o];
        }
    }
}

extern "C" void kernel_launch(void* const* d_in, const int* in_sizes, int n_in,
                              void* d_out, int out_size, void* d_ws, size_t ws_size,
                              hipStream_t stream) {
    const float* x     = (const float*)d_in[0];
    const int*   eidx  = (const int*)d_in[1];
    const float* eattr = (const float*)d_in[2];
    const float* nn1_w = (const float*)d_in[3];
    const float* nn1_b = (const float*)d_in[4];
    const float* root1 = (const float*)d_in[5];
    const float* bias1 = (const float*)d_in[6];
    const float* nn2_w = (const float*)d_in[7];
    const float* nn2_b = (const float*)d_in[8];
    const float* root2 = (const float*)d_in[9];
    const float* bias2 = (const float*)d_in[10];
    const float* nn3_w = (const float*)d_in[11];
    const float* nn3_b = (const float*)d_in[12];
    const float* root3 = (const float*)d_in[13];
    const float* bias3 = (const float*)d_in[14];
    float* out = (float*)d_out;

    const int N = in_sizes[0] / 2;
    const int E = in_sizes[2] / 2;
    const int* src = eidx;
    const int* dst = eidx + E;

    char* ws = (char*)d_ws;
    size_t off = 0;
    auto alloc = [&](size_t bytes, size_t align) -> char* {
        off = (off + align - 1) / align * align;
        char* p = ws + off;
        off += bytes;
        return p;
    };
    int*   counts = (int*)alloc((size_t)N * 4, 16);
    uint2* edata  = (uint2*)alloc((size_t)N * CAP * 8, 16);
    uint2* Ypk_a  = (uint2*)alloc((size_t)N * 16 * 8, 16);
    uint2* Ypk_b  = (uint2*)alloc((size_t)N * 16 * 8, 16);
    float* Y6f    = (float*)alloc((size_t)N * 8 * 4, 16);
    uint2* Y6pk   = (uint2*)alloc((size_t)N * 2 * 8, 16);
    (void)ws_size; (void)n_in; (void)out_size;

    const int zblocks = (N + BLK - 1) / BLK;

    // --- counts=0; then count+scatter + pre1 (one grid-stride kernel) ---
    zero1_kernel<<<zblocks, BLK, 0, stream>>>(counts, N);
    fillpre_kernel<<<GRID, BLK, 0, stream>>>(src, dst, eattr, counts, edata, E,
                                             x, nn1_w, nn1_b, root1, Ypk_a, N);

    // --- layers 1-3: agg + next-layer pre + final-layer partial (ping-pong) ---
    aggpre16L_kernel<<<GRID, BLK, 0, stream>>>(counts, edata, Ypk_a, bias1,
                                               nn2_w, nn2_b, root2,
                                               nn3_w, nn3_b, root3,
                                               Ypk_b, Y6f, 0, 1, N);
    aggpre16L_kernel<<<GRID, BLK, 0, stream>>>(counts, edata, Ypk_b, bias2,
                                               nn2_w, nn2_b, root2,
                                               nn3_w, nn3_b, root3,
                                               Ypk_a, Y6f, 16, 0, N);
    aggpre16L_kernel<<<GRID, BLK, 0, stream>>>(counts, edata, Ypk_a, bias2,
                                               nn2_w, nn2_b, root2,
                                               nn3_w, nn3_b, root3,
                                               Ypk_b, Y6f, 32, 0, N);

    // --- layer 4: agg + pack final Y6 ---
    agg4_kernel<<<GRID, BLK, 0, stream>>>(counts, edata, Ypk_b, bias2,
                                          nn3_w, nn3_b, root3, Y6f, Y6pk, 48, N);

    // --- final aggregation (fout=2, no lrelu) ---
    edge_agg2_wave<<<GRID, BLK, 0, stream>>>(counts, edata, Y6pk, bias3, out, N);
}

// Round 20
// 120.701 us; speedup vs baseline: 9.8714x; 1.0945x over previous
//
#include <hip/hip_runtime.h>
#include <hip/hip_fp16.h>

// NNConv GNN: 5 conv layers, fixed graph (N=40000, E=400000).
// R-ladder: 317 -> 228 -> 205 -> 190 -> 184 -> 148.6 -> 148.1 -> 143.6 ->
// 132.1 (R19 grid-stride @2048 WGs; CP-ramp confirmed ~2us/fat kernel).
// Structure: 5 message-passing rounds are inherently sequential (agg(l) needs
// Y(l) of ALL neighbors) -> 7 dispatches minimum; grid.sync costs ~220us
// (R15), so dispatch boundaries are the only global-barrier mechanism.
// R20: (a) transposed weight tables M2T/M3T (built in prep kernel, 6KB,
// L1-resident): projection weight access 16 strided scalars -> 4x float4;
// M3 partial -> 1x float2. (b) 4-deep prefetch (tail only for deg>16, 2.2%).
// Decisive probe: if dur stays >=130, boundaries (~14us each) dominate ->
// structural floor.

#define NEG_SLOPE 0.01f
#define CAP 48
#define BLK 256
#define GRID 2048

__device__ __forceinline__ unsigned pk2(float a, float b) {
    __half2 h = __floats2half2_rn(a, b);
    return *reinterpret_cast<unsigned*>(&h);
}
__device__ __forceinline__ float2 upk2(unsigned u) {
    __half2 h = *reinterpret_cast<__half2*>(&u);
    return __half22float2(h);
}

// Zero counts + build transposed weight tables.
// M2T[blk][o][i] = M2_blk[i][o]  (blk: 0=A0 1=A1 2=B 3=root), 1024 floats.
// M3T[j][i]     = M3row(j,i), j=(blk<<1)|oo, i=0..63, 512 floats.
__global__ void __launch_bounds__(BLK, 8)
prep_kernel(int* __restrict__ counts, int N,
            const float* __restrict__ nnw2, const float* __restrict__ nnb2,
            const float* __restrict__ root2,
            const float* __restrict__ nnw3, const float* __restrict__ nnb3,
            const float* __restrict__ root3,
            float* __restrict__ M2T, float* __restrict__ M3T) {
    int tid = blockIdx.x * BLK + threadIdx.x;
    if (tid < N) counts[tid] = 0;
    if (tid < 1024) {
        int blk = tid >> 8, o = (tid >> 4) & 15, i = tid & 15;
        float v;
        if (blk == 0)      v = nnw2[(i * 16 + o) * 2];
        else if (blk == 1) v = nnw2[(i * 16 + o) * 2 + 1];
        else if (blk == 2) v = nnb2[i * 16 + o];
        else               v = root2[i * 16 + o];
        M2T[tid] = v;
    } else if (tid < 1536) {
        int t = tid - 1024;
        int j = t >> 6, i = t & 63;
        int blk = j >> 1, oo = j & 1;
        float v;
        if (blk == 0)      v = nnw3[(i * 2 + oo) * 2];
        else if (blk == 1) v = nnw3[(i * 2 + oo) * 2 + 1];
        else if (blk == 2) v = nnb3[i * 2 + oo];
        else               v = root3[i * 2 + oo];
        M3T[t] = v;
    }
}

// Grid-stride: loop 1 scatters edges into buckets (slot = atomic return);
// loop 2 computes layer-1 projections (fin=2) packed fp16 into Ypk.
__global__ void __launch_bounds__(BLK, 8)
fillpre_kernel(const int* __restrict__ src, const int* __restrict__ dst,
               const float* __restrict__ ea, int* __restrict__ counts,
               uint2* __restrict__ edata, int E,
               const float* __restrict__ x,
               const float* __restrict__ nnw, const float* __restrict__ nnb,
               const float* __restrict__ root,
               uint2* __restrict__ Ypk, int N) {
    const int tid = blockIdx.x * BLK + threadIdx.x;
    const int nth = GRID * BLK;
    for (int e = tid; e < E; e += nth) {
        int d = dst[e];
        int slot = atomicAdd(&counts[d], 1);
        if (slot < CAP)
            edata[(size_t)d * CAP + slot] =
                make_uint2((unsigned)src[e], pk2(ea[2 * e], ea[2 * e + 1]));
    }
    for (int t = tid; t < N * 16; t += nth) {
        int n = t >> 4, o = t & 15;
        float x0 = x[n * 2], x1 = x[n * 2 + 1];
        int k0 = o, k1 = 16 + o;
        float a0 = x0 * nnw[2 * k0] + x1 * nnw[2 * k1];
        float a1 = x0 * nnw[2 * k0 + 1] + x1 * nnw[2 * k1 + 1];
        float ab = x0 * nnb[k0] + x1 * nnb[k1];
        float ar = x0 * root[k0] + x1 * root[k1];
        Ypk[(size_t)n * 16 + o] = make_uint2(pk2(a0, a1), pk2(ab, ar));
    }
}

// Masked edge term: load ALWAYS issued (src clamped for poison slots);
// result zeroed when invalid -> compiler batches independent gathers.
__device__ __forceinline__ float mterm(uint2 ed, const uint2* __restrict__ Yin,
                                       int o, bool valid, int N) {
    unsigned s = ed.x;
    if (s >= (unsigned)N) s = 0;
    float2 eaf = upk2(ed.y);
    uint2 ys = Yin[(size_t)s * 16 + o];
    float2 y01 = upk2(ys.x);
    float2 y23 = upk2(ys.y);
    float t = fmaf(eaf.x, y01.x, fmaf(eaf.y, y01.y, y23.x));
    return valid ? t : 0.f;
}

// agg core: 4 groups x 16 ch; 4-deep parallel prefetch + rare uniform tail.
__device__ __forceinline__ float agg16_acc(const int* __restrict__ counts,
                                           const uint2* __restrict__ edata,
                                           const uint2* __restrict__ Yin,
                                           int w, int o, int g, int N, int& degout) {
    int deg = counts[w]; deg = deg < CAP ? deg : CAP;
    degout = deg;
    const uint2* row = edata + (size_t)w * CAP;
    uint2 e0 = row[g];          // g    <= 3  < CAP
    uint2 e1 = row[g + 4];      // g+4  <= 7
    uint2 e2 = row[g + 8];      // g+8  <= 11
    uint2 e3 = row[g + 12];     // g+12 <= 15 < CAP
    float acc = mterm(e0, Yin, o, g < deg, N);
    acc += mterm(e1, Yin, o, g + 4 < deg, N);
    acc += mterm(e2, Yin, o, g + 8 < deg, N);
    acc += mterm(e3, Yin, o, g + 12 < deg, N);
    for (int k = g + 16; k < deg; k += 4)  // P(deg>16) ~ 2.2%, wave-uniform
        acc += mterm(row[k], Yin, o, true, N);
    return acc;
}

// Grid-stride fused layer: agg (fout=16, lrelu) -> r; next-layer projections
// -> Yout (packed fp16, via M2T); final-layer f32 partial into Y6f (via M3T).
__global__ void __launch_bounds__(BLK, 8)
aggpre16L_kernel(const int* __restrict__ counts, const uint2* __restrict__ edata,
                 const uint2* __restrict__ Yin, const float* __restrict__ bias,
                 const float* __restrict__ M2T, const float* __restrict__ M3T,
                 uint2* __restrict__ Yout, float* __restrict__ Y6f,
                 int m3base, int first, int N) {
    const int lane = threadIdx.x & 63;
    const int o = lane & 15, g = lane >> 4;
    const int wid0 = (int)((blockIdx.x * BLK + threadIdx.x) >> 6);
    const int nw = (GRID * BLK) >> 6;
    const float4* m2row = (const float4*)(M2T + g * 256 + o * 16);  // 4x float4
    const int j = lane & 7, g8 = lane >> 3;
    for (int w = wid0; w < N; w += nw) {
        int deg;
        float acc = agg16_acc(counts, edata, Yin, w, o, g, N, deg);
        acc += __shfl_xor(acc, 16, 64);
        acc += __shfl_xor(acc, 32, 64);
        float invdeg = 1.0f / (float)(deg > 1 ? deg : 1);
        float rootown = upk2(Yin[(size_t)w * 16 + o].y).y;
        float r = acc * invdeg + rootown + bias[o];
        r = r > 0.f ? r : NEG_SLOPE * r;
        // next-layer projections via transposed table: contiguous 16 floats
        {
            float4 m0 = m2row[0], m1 = m2row[1], m2 = m2row[2], m3 = m2row[3];
            float y = 0.f;
            y = fmaf(__shfl(r, 0, 64), m0.x, y);
            y = fmaf(__shfl(r, 1, 64), m0.y, y);
            y = fmaf(__shfl(r, 2, 64), m0.z, y);
            y = fmaf(__shfl(r, 3, 64), m0.w, y);
            y = fmaf(__shfl(r, 4, 64), m1.x, y);
            y = fmaf(__shfl(r, 5, 64), m1.y, y);
            y = fmaf(__shfl(r, 6, 64), m1.z, y);
            y = fmaf(__shfl(r, 7, 64), m1.w, y);
            y = fmaf(__shfl(r, 8, 64), m2.x, y);
            y = fmaf(__shfl(r, 9, 64), m2.y, y);
            y = fmaf(__shfl(r, 10, 64), m2.z, y);
            y = fmaf(__shfl(r, 11, 64), m2.w, y);
            y = fmaf(__shfl(r, 12, 64), m3.x, y);
            y = fmaf(__shfl(r, 13, 64), m3.y, y);
            y = fmaf(__shfl(r, 14, 64), m3.z, y);
            y = fmaf(__shfl(r, 15, 64), m3.w, y);
            float p16 = __shfl_xor(y, 16, 64);
            float p32 = __shfl_xor(y, 32, 64);
            float p48 = __shfl_xor(y, 48, 64);
            if (g == 0) Yout[(size_t)w * 16 + o] = make_uint2(pk2(y, p16), pk2(p32, p48));
        }
        // final-layer f32 partial via M3T: one float2 per lane
        {
            float2 m = *(const float2*)(M3T + j * 64 + m3base + g8 * 2);
            float p = fmaf(__shfl(r, g8 * 2, 64), m.x,
                           __shfl(r, g8 * 2 + 1, 64) * m.y);
            p += __shfl_xor(p, 8, 64);
            p += __shfl_xor(p, 16, 64);
            p += __shfl_xor(p, 32, 64);
            if (lane < 8) {
                float* y6 = Y6f + (size_t)w * 8 + (j & 1) * 4 + (j >> 1);
                *y6 = first ? p : (*y6 + p);
            }
        }
    }
}

// Grid-stride layer-4: agg (lrelu) + final Y6 sum, packed fp16 to Y6pk.
__global__ void __launch_bounds__(BLK, 8)
agg4_kernel(const int* __restrict__ counts, const uint2* __restrict__ edata,
            const uint2* __restrict__ Yin, const float* __restrict__ bias,
            const float* __restrict__ M3T,
            const float* __restrict__ Y6f, uint2* __restrict__ Y6pk,
            int m3base, int N) {
    const int lane = threadIdx.x & 63;
    const int o = lane & 15, g = lane >> 4;
    const int j = lane & 7, g8 = lane >> 3;
    const int wid0 = (int)((blockIdx.x * BLK + threadIdx.x) >> 6);
    const int nw = (GRID * BLK) >> 6;
    for (int w = wid0; w < N; w += nw) {
        int deg;
        float acc = agg16_acc(counts, edata, Yin, w, o, g, N, deg);
        acc += __shfl_xor(acc, 16, 64);
        acc += __shfl_xor(acc, 32, 64);
        float invdeg = 1.0f / (float)(deg > 1 ? deg : 1);
        float rootown = upk2(Yin[(size_t)w * 16 + o].y).y;
        float r = acc * invdeg + rootown + bias[o];
        r = r > 0.f ? r : NEG_SLOPE * r;
        float2 m = *(const float2*)(M3T + j * 64 + m3base + g8 * 2);
        float p = fmaf(__shfl(r, g8 * 2, 64), m.x,
                       __shfl(r, g8 * 2 + 1, 64) * m.y);
        p += __shfl_xor(p, 8, 64);
        p += __shfl_xor(p, 16, 64);
        p += __shfl_xor(p, 32, 64);
        float tot = Y6f[(size_t)w * 8 + (j & 1) * 4 + (j >> 1)] + p;
        float t1 = __shfl_xor(tot, 2, 64);
        float t2 = __shfl_xor(tot, 4, 64);
        float t3 = __shfl_xor(tot, 6, 64);
        if (lane < 2)
            Y6pk[(size_t)w * 2 + lane] = make_uint2(pk2(tot, t1), pk2(t2, t3));
    }
}

// Grid-stride final aggregation, fout=2: 32 edge-groups x 2 channels.
__global__ void __launch_bounds__(BLK, 8)
edge_agg2_wave(const int* __restrict__ counts, const uint2* __restrict__ edata,
               const uint2* __restrict__ Y6pk, const float* __restrict__ bias,
               float* __restrict__ Out, int N) {
    const int lane = threadIdx.x & 63;
    const int o = lane & 1, g = lane >> 1;
    const int wid0 = (int)((blockIdx.x * BLK + threadIdx.x) >> 6);
    const int nw = (GRID * BLK) >> 6;
    for (int w = wid0; w < N; w += nw) {
        int deg = counts[w]; deg = deg < CAP ? deg : CAP;
        const uint2* row = edata + (size_t)w * CAP;
        uint2 e0 = row[g];
        float acc;
        {
            unsigned s = e0.x; if (s >= (unsigned)N) s = 0;
            float2 eaf = upk2(e0.y);
            uint2 q = Y6pk[(size_t)s * 2 + o];
            float2 q01 = upk2(q.x);
            float2 q23 = upk2(q.y);
            float t = fmaf(eaf.x, q01.x, fmaf(eaf.y, q01.y, q23.x));
            acc = (g < deg) ? t : 0.f;
        }
        if (deg > 32) {
            int k1 = g + 32 < CAP ? g + 32 : CAP - 1;
            uint2 e1 = row[k1];
            unsigned s = e1.x; if (s >= (unsigned)N) s = 0;
            float2 eaf = upk2(e1.y);
            uint2 q = Y6pk[(size_t)s * 2 + o];
            float2 q01 = upk2(q.x);
            float2 q23 = upk2(q.y);
            float t = fmaf(eaf.x, q01.x, fmaf(eaf.y, q01.y, q23.x));
            acc += (g + 32 < deg) ? t : 0.f;
        }
#pragma unroll
        for (int m = 2; m <= 32; m <<= 1) acc += __shfl_xor(acc, m, 64);
        if (lane < 2) {
            float invdeg = 1.0f / (float)(deg > 1 ? deg : 1);
            float rootown = upk2(Y6pk[(size_t)w * 2 + o].y).y;
            Out[(size_t)w * 2 + o] = acc * invdeg + rootown + bias[o];
        }
    }
}

extern "C" void kernel_launch(void* const* d_in, const int* in_sizes, int n_in,
                              void* d_out, int out_size, void* d_ws, size_t ws_size,
                              hipStream_t stream) {
    const float* x     = (const float*)d_in[0];
    const int*   eidx  = (const int*)d_in[1];
    const float* eattr = (const float*)d_in[2];
    const float* nn1_w = (const float*)d_in[3];
    const float* nn1_b = (const float*)d_in[4];
    const float* root1 = (const float*)d_in[5];
    const float* bias1 = (const float*)d_in[6];
    const float* nn2_w = (const float*)d_in[7];
    const float* nn2_b = (const float*)d_in[8];
    const float* root2 = (const float*)d_in[9];
    const float* bias2 = (const float*)d_in[10];
    const float* nn3_w = (const float*)d_in[11];
    const float* nn3_b = (const float*)d_in[12];
    const float* root3 = (const float*)d_in[13];
    const float* bias3 = (const float*)d_in[14];
    float* out = (float*)d_out;

    const int N = in_sizes[0] / 2;
    const int E = in_sizes[2] / 2;
    const int* src = eidx;
    const int* dst = eidx + E;

    char* ws = (char*)d_ws;
    size_t off = 0;
    auto alloc = [&](size_t bytes, size_t align) -> char* {
        off = (off + align - 1) / align * align;
        char* p = ws + off;
        off += bytes;
        return p;
    };
    int*   counts = (int*)alloc((size_t)N * 4, 16);
    uint2* edata  = (uint2*)alloc((size_t)N * CAP * 8, 16);
    uint2* Ypk_a  = (uint2*)alloc((size_t)N * 16 * 8, 16);
    uint2* Ypk_b  = (uint2*)alloc((size_t)N * 16 * 8, 16);
    float* Y6f    = (float*)alloc((size_t)N * 8 * 4, 16);
    uint2* Y6pk   = (uint2*)alloc((size_t)N * 2 * 8, 16);
    float* M2T    = (float*)alloc(1024 * 4, 16);
    float* M3T    = (float*)alloc(512 * 4, 16);
    (void)ws_size; (void)n_in; (void)out_size;

    const int zblocks = (N + BLK - 1) / BLK;

    // --- counts=0 + transposed weight tables; then scatter + pre1 ---
    prep_kernel<<<zblocks, BLK, 0, stream>>>(counts, N, nn2_w, nn2_b, root2,
                                             nn3_w, nn3_b, root3, M2T, M3T);
    fillpre_kernel<<<GRID, BLK, 0, stream>>>(src, dst, eattr, counts, edata, E,
                                             x, nn1_w, nn1_b, root1, Ypk_a, N);

    // --- layers 1-3: agg + next-layer pre + final-layer partial (ping-pong) ---
    aggpre16L_kernel<<<GRID, BLK, 0, stream>>>(counts, edata, Ypk_a, bias1,
                                               M2T, M3T, Ypk_b, Y6f, 0, 1, N);
    aggpre16L_kernel<<<GRID, BLK, 0, stream>>>(counts, edata, Ypk_b, bias2,
                                               M2T, M3T, Ypk_a, Y6f, 16, 0, N);
    aggpre16L_kernel<<<GRID, BLK, 0, stream>>>(counts, edata, Ypk_a, bias2,
                                               M2T, M3T, Ypk_b, Y6f, 32, 0, N);

    // --- layer 4: agg + pack final Y6 ---
    agg4_kernel<<<GRID, BLK, 0, stream>>>(counts, edata, Ypk_b, bias2,
                                          M3T, Y6f, Y6pk, 48, N);

    // --- final aggregation (fout=2, no lrelu) ---
    edge_agg2_wave<<<GRID, BLK, 0, stream>>>(counts, edata, Y6pk, bias3, out, N);
}